// Round 1
// 616.446 us; speedup vs baseline: 1.0683x; 1.0683x over previous
//
#include <hip/hip_runtime.h>
#include <cstdint>
#include <cstddef>

constexpr int B = 8, C = 32, H = 512, W = 512;
constexpr int HW = H * W;

__device__ __forceinline__ float sigmoidf_(float z) {
    return 1.0f / (1.0f + __expf(-z));
}

// round-to-nearest-even f32 -> bf16 (bit trick; inputs finite/moderate)
__device__ __forceinline__ unsigned short bf16rne(float x) {
    unsigned int b = __float_as_uint(x);
    return (unsigned short)((b + 0x7FFFu + ((b >> 16) & 1u)) >> 16);
}
__device__ __forceinline__ float bf16tof(unsigned short h) {
    return __uint_as_float(((unsigned int)h) << 16);
}

typedef short s8v  __attribute__((ext_vector_type(8)));   // 8 bf16 (4 VGPR) MFMA operand
typedef float f16v __attribute__((ext_vector_type(16)));  // 32x32 MFMA accumulator

// ---------------------------------------------------------------------------
// Kernel 1 (UNCHANGED): patch gate + 1x1 conv + channel max/mean
// ---------------------------------------------------------------------------
__global__ __launch_bounds__(256, 4) void k1_gate_conv(
    const float* __restrict__ x, const float* __restrict__ mlp_w,
    const float* __restrict__ mlp_b, const float* __restrict__ conv_w,
    const float* __restrict__ conv_b, float* __restrict__ fs,
    float* __restrict__ cm, float* __restrict__ ca)
{
    __shared__ float xs[32][256];   // [c][row*128+col]
    __shared__ float gs[32][64];    // [c][patch_col]
    const int t  = threadIdx.x;
    const int c0 = blockIdx.x * 128;
    const int h0 = blockIdx.y * 2;
    const int b  = blockIdx.z;

    #pragma unroll
    for (int k = 0; k < 8; ++k) {
        int li = k * 256 + t;
        int c = li >> 6, q = li & 63;
        int p = q * 4;
        int row = p >> 7, col = p & 127;
        const float4 v = *(const float4*)(x + ((size_t)(b * C + c) * H + h0 + row) * W + c0 + col);
        *(float4*)&xs[c][p] = v;
    }
    __syncthreads();

    const float gw = mlp_w[0];
    const float gb = 2.0f * mlp_b[0];
    #pragma unroll
    for (int k = 0; k < 8; ++k) {
        int gi = k * 256 + t;        // 32 ch * 64 patches = 2048
        int c = gi >> 6, wp = gi & 63;
        float a0 = xs[c][2 * wp],       a1 = xs[c][2 * wp + 1];
        float a2 = xs[c][128 + 2 * wp], a3 = xs[c][129 + 2 * wp];
        float mx = fmaxf(fmaxf(a0, a1), fmaxf(a2, a3));
        float av = 0.25f * ((a0 + a1) + (a2 + a3));
        gs[c][wp] = sigmoidf_(fmaf(mx + av, gw, gb));
    }
    __syncthreads();

    const int row = t >> 7, col = t & 127, wp = col >> 1;
    float xv[32], xg[32];
    #pragma unroll
    for (int c = 0; c < 32; ++c) {
        float v = xs[c][t];
        xv[c] = v;
        xg[c] = v * gs[c][wp];
    }
    float cmax = -3.4e38f, csum = 0.0f;
    const size_t pixoff = ((size_t)(b * C) * H + h0 + row) * W + c0 + col;
    #pragma unroll 4
    for (int o = 0; o < 32; ++o) {
        const float* wr = conv_w + o * 64;     // wave-uniform -> s_load
        float acc0 = conv_b[o], acc1 = 0.0f;
        #pragma unroll
        for (int c = 0; c < 32; ++c) {
            acc0 = fmaf(xg[c], wr[c],      acc0);
            acc1 = fmaf(xv[c], wr[32 + c], acc1);
        }
        float acc = acc0 + acc1;
        fs[pixoff + (size_t)o * HW] = acc;
        cmax = fmaxf(cmax, acc);
        csum += acc;
    }
    const size_t pp = ((size_t)b * H + h0 + row) * W + c0 + col;
    cm[pp] = cmax;
    ca[pp] = csum * (1.0f / 32.0f);
}

// ---------------------------------------------------------------------------
// Kernel 2 (REWRITTEN): 7x7 conv (2ch->32ch SAME) via bf16 split MFMA,
// then out = sigmoid(att) * fs, in place.
//
// GEMM mapping per 32-px row strip: D[oc=32][px=32] = A[oc][k16] x B[k16][px],
//   k = 8*j + dx  (j: 0=cm,1=ca; dx 0..7, slot 7 carries zero weight),
//   looped over dy=0..6 and accumulated in one f32x16 acc (C-in = bias).
// Split-bf16 for accuracy: v = hi + lo (each bf16 RNE); 3 MFMA terms
//   Whi*Bhi + Whi*Blo + Wlo*Bhi  (dropped Wlo*Blo ~ 2^-18 rel).
// A-frag layout: lane l holds row=l&31 (=oc), k=8*(l>>5)+q  -> per-lane
//   weights w[o=l&31][j=l>>5][dy][q] (q=7 -> 0).
// B-frag layout: lane l holds col=l&31 (=px), k=8*(l>>5)+q -> lane reads
//   plane j=l>>5, window row y+dy, cols xl..xl+7 (xl = wv*32 + (l&31)).
//   Built from 5 aligned dword LDS reads + 16-bit funnel shift for odd xl.
// D layout (verified m74/m101): col=lane&31 (=px), row=(r&3)+8*(r>>2)+4*(l>>5).
//
// LDS window: 4 bf16 planes [comp(hi/lo)][j(cm/ca)] x 14 rows x 144 cols
//   = 16128 B.  Plane stride 1008 dwords == 16 (mod 32 banks) -> the two
//   half-wave planes hit disjoint bank halves (conflict-free b32 reads).
// Tile: 128 cols x 8 rows, 4 waves (1 strip each), grid (4, 64, 8).
// ---------------------------------------------------------------------------
__global__ __launch_bounds__(256, 3) void k2_conv7_mfma(
    const float* __restrict__ cm, const float* __restrict__ ca,
    const float* __restrict__ convout_w, const float* __restrict__ convout_b,
    float* __restrict__ io /* fs in, final out, in-place */)
{
    __shared__ unsigned short win[4 * 14 * 144];   // hi{cm,ca}, lo{cm,ca}
    const int t  = threadIdx.x;
    const int x0 = blockIdx.x * 128;
    const int y0 = blockIdx.y * 8;
    const int b  = blockIdx.z;

    // ---- stage cm/ca window -> bf16 hi/lo planes (zero-padded SAME) ----
    // n = j*2016 + row*144 + col over 2*14*144 = 4032 positions;
    // hi at win[n], lo at win[n + 4032].
    #pragma unroll
    for (int k = 0; k < 16; ++k) {
        int n = k * 256 + t;
        if (n < 4032) {
            int j   = (n >= 2016) ? 1 : 0;
            int rem = n - j * 2016;
            int row = rem / 144;
            int col = rem - row * 144;
            int gy = y0 - 3 + row;
            int gx = x0 - 3 + col;
            float v = 0.0f;
            if ((unsigned)gy < (unsigned)H && (unsigned)gx < (unsigned)W)
                v = (j ? ca : cm)[(size_t)b * HW + (size_t)gy * W + gx];
            unsigned short hb = bf16rne(v);
            unsigned short lb = bf16rne(v - bf16tof(hb));
            win[n]        = hb;
            win[n + 4032] = lb;
        }
    }

    // ---- per-lane weight fragments (independent of staging) ----
    const int l  = t & 63;
    const int wv = t >> 6;          // wave id = strip id
    const int o  = l & 31;          // A row (oc) / B col (px)
    const int j  = l >> 5;          // k-half: input plane select
    s8v whi[7], wlo[7];
    #pragma unroll
    for (int dy = 0; dy < 7; ++dy) {
        #pragma unroll
        for (int q = 0; q < 8; ++q) {
            float wf = (q < 7) ? convout_w[(o * 2 + j) * 49 + dy * 7 + q] : 0.0f;
            unsigned short hb = bf16rne(wf);
            unsigned short lb = bf16rne(wf - bf16tof(hb));
            whi[dy][q] = (short)hb;
            wlo[dy][q] = (short)lb;
        }
    }
    float bias[16];
    #pragma unroll
    for (int r = 0; r < 16; ++r)
        bias[r] = convout_b[(r & 3) + 8 * (r >> 2) + 4 * j];
    __syncthreads();

    const int xl  = wv * 32 + o;    // local pixel col 0..127
    const int q0  = xl >> 1;        // dword index within row
    const bool odd = (xl & 1) != 0;

    #pragma unroll 1
    for (int y = 0; y < 8; ++y) {
        f16v acc;
        #pragma unroll
        for (int r = 0; r < 16; ++r) acc[r] = bias[r];

        #pragma unroll
        for (int dy = 0; dy < 7; ++dy) {
            const unsigned int* rp =
                (const unsigned int*)win + (size_t)(y + dy) * 72 + j * 1008 + q0;
            unsigned int d0 = rp[0], d1 = rp[1], d2 = rp[2], d3 = rp[3], d4 = rp[4];
            const unsigned int* rp2 = rp + 2016;   // lo planes (+4032 elems)
            unsigned int e0 = rp2[0], e1 = rp2[1], e2 = rp2[2], e3 = rp2[3], e4 = rp2[4];

            union { unsigned int u[4]; s8v s; } Bh, Bl;
            if (odd) {
                Bh.u[0] = (d0 >> 16) | (d1 << 16);
                Bh.u[1] = (d1 >> 16) | (d2 << 16);
                Bh.u[2] = (d2 >> 16) | (d3 << 16);
                Bh.u[3] = (d3 >> 16) | (d4 << 16);
                Bl.u[0] = (e0 >> 16) | (e1 << 16);
                Bl.u[1] = (e1 >> 16) | (e2 << 16);
                Bl.u[2] = (e2 >> 16) | (e3 << 16);
                Bl.u[3] = (e3 >> 16) | (e4 << 16);
            } else {
                Bh.u[0] = d0; Bh.u[1] = d1; Bh.u[2] = d2; Bh.u[3] = d3;
                Bl.u[0] = e0; Bl.u[1] = e1; Bl.u[2] = e2; Bl.u[3] = e3;
            }
            acc = __builtin_amdgcn_mfma_f32_32x32x16_bf16(whi[dy], Bh.s, acc, 0, 0, 0);
            acc = __builtin_amdgcn_mfma_f32_32x32x16_bf16(whi[dy], Bl.s, acc, 0, 0, 0);
            acc = __builtin_amdgcn_mfma_f32_32x32x16_bf16(wlo[dy], Bh.s, acc, 0, 0, 0);
        }

        // ---- epilogue: out = sigmoid(att) * fs, coalesced per-reg rows ----
        const int Y = y0 + y;
        const int X = x0 + xl;
        #pragma unroll
        for (int r = 0; r < 16; ++r) {
            int oc = (r & 3) + 8 * (r >> 2) + 4 * j;
            size_t a = ((size_t)(b * C + oc) * H + Y) * W + X;
            float f = io[a];
            io[a] = f * sigmoidf_(acc[r]);
        }
    }
}

extern "C" void kernel_launch(void* const* d_in, const int* in_sizes, int n_in,
                              void* d_out, int out_size, void* d_ws, size_t ws_size,
                              hipStream_t stream)
{
    const float* x         = (const float*)d_in[0];
    const float* mlp_w     = (const float*)d_in[1];
    const float* mlp_b     = (const float*)d_in[2];
    const float* conv_w    = (const float*)d_in[3];
    const float* conv_b    = (const float*)d_in[4];
    const float* convout_w = (const float*)d_in[5];
    const float* convout_b = (const float*)d_in[6];

    float* out = (float*)d_out;             // fs lives here between kernels
    float* cm  = (float*)d_ws;              // 8 MiB
    float* ca  = cm + (size_t)B * HW;       // 8 MiB (ws needs 16 MiB)

    k1_gate_conv<<<dim3(4, 256, 8), 256, 0, stream>>>(
        x, mlp_w, mlp_b, conv_w, conv_b, out, cm, ca);
    k2_conv7_mfma<<<dim3(4, 64, 8), 256, 0, stream>>>(
        cm, ca, convout_w, convout_b, out);
}

// Round 3
// 592.913 us; speedup vs baseline: 1.1107x; 1.0397x over previous
//
#include <hip/hip_runtime.h>
#include <cstdint>
#include <cstddef>

constexpr int B = 8, C = 32, H = 512, W = 512;
constexpr int HW = H * W;

__device__ __forceinline__ float sigmoidf_(float z) {
    return 1.0f / (1.0f + __expf(-z));
}

// round-to-nearest-even f32 -> bf16 (bit trick; inputs finite/moderate)
__device__ __forceinline__ unsigned int bf16rne(float x) {
    unsigned int b = __float_as_uint(x);
    return (b + 0x7FFFu + ((b >> 16) & 1u)) >> 16;
}
__device__ __forceinline__ float bf16tof(unsigned int h) {
    return __uint_as_float(h << 16);
}

typedef uint2 __attribute__((may_alias)) uint2_ma;   // LDS write punning: keep
                                                     // program order vs u16 reads

// split v = hi + lo, both bf16; pack 4 values into hi/lo uint2 (2 bf16 per u32)
__device__ __forceinline__ void split4(float a, float b2, float c, float d,
                                       uint2& hi, uint2& lo) {
    unsigned ha = bf16rne(a), hb = bf16rne(b2), hc = bf16rne(c), hd = bf16rne(d);
    unsigned la = bf16rne(a - bf16tof(ha)), lb = bf16rne(b2 - bf16tof(hb));
    unsigned lc = bf16rne(c - bf16tof(hc)), ld = bf16rne(d - bf16tof(hd));
    hi = make_uint2(ha | (hb << 16), hc | (hd << 16));
    lo = make_uint2(la | (lb << 16), lc | (ld << 16));
}

typedef __attribute__((address_space(1))) const void gv_t;
typedef __attribute__((address_space(3))) void lv_t;

typedef short s8v  __attribute__((ext_vector_type(8)));   // 8 bf16 (4 VGPR) MFMA operand
typedef float f16v __attribute__((ext_vector_type(16)));  // 32x32 MFMA accumulator

// ---------------------------------------------------------------------------
// Kernel 1: patch gate + 1x1 conv via split-bf16 MFMA + ch max/mean
// (structure as round 2; see comments there)
// ---------------------------------------------------------------------------
__global__ __launch_bounds__(256, 4) void k1_gate_conv_mfma(
    const float* __restrict__ x, const float* __restrict__ mlp_w,
    const float* __restrict__ mlp_b, const float* __restrict__ conv_w,
    const float* __restrict__ conv_b, float* __restrict__ fs,
    float* __restrict__ cm, float* __restrict__ ca)
{
    __shared__ float xs[32][128];          // [c][row*64+col] fp32
    __shared__ float gs[32][32];           // [c][patch_col] gate
    __shared__ unsigned short Bb[4][2304]; // per-wave: {xg,xv} x {hi,lo} x [16][36]

    const int t  = threadIdx.x;
    const int l  = t & 63;
    const int wv = t >> 6;
    const int x0 = blockIdx.x * 64;
    const int h0 = blockIdx.y * 2;
    const int b  = blockIdx.z;

    // ---- phase 1: DMA-stage x tile into xs (4 x 1KiB per wave) ----
    #pragma unroll
    for (int i = 0; i < 4; ++i) {
        const int m   = wv * 4 + i;          // wave-uniform
        const int f   = m * 256 + l * 4;     // f32 flat index into xs
        const int c   = f >> 7;
        const int px  = f & 127;
        const int row = px >> 6, col = px & 63;
        const float* src = x + ((size_t)(b * C + c) * H + h0 + row) * W + x0 + col;
        float* dst = &xs[0][0] + m * 256;    // wave-uniform base; HW adds lane*16B
        __builtin_amdgcn_global_load_lds((gv_t*)src, (lv_t*)dst, 16, 0, 0);
    }

    // ---- weight/bias fragments (global, L2/L3-hot; overlap with DMA) ----
    const int o = l & 31;        // A row (oc) / B,D col (px)
    const int j = l >> 5;        // k-half select
    s8v whi[4], wlo[4];
    #pragma unroll
    for (int s = 0; s < 4; ++s) {
        #pragma unroll
        for (int q = 0; q < 8; ++q) {
            float wf = conv_w[o * 64 + 16 * s + 8 * j + q];
            unsigned hb = bf16rne(wf);
            whi[s][q] = (short)hb;
            wlo[s][q] = (short)bf16rne(wf - bf16tof(hb));
        }
    }
    f16v acc;
    #pragma unroll
    for (int r = 0; r < 16; ++r) acc[r] = conv_b[(r & 3) + 8 * (r >> 2) + 4 * j];

    __syncthreads();

    // ---- phase 2: gates: sigmoid((max+mean)*w + 2b), 1024 per block ----
    const float gw = mlp_w[0];
    const float gb = 2.0f * mlp_b[0];
    #pragma unroll
    for (int it = 0; it < 4; ++it) {
        int gi = it * 256 + t;
        int c = gi >> 5, wp = gi & 31;
        float2 fa = *(const float2*)&xs[c][2 * wp];
        float2 fb = *(const float2*)&xs[c][64 + 2 * wp];
        float mx = fmaxf(fmaxf(fa.x, fa.y), fmaxf(fb.x, fb.y));
        float av = 0.25f * ((fa.x + fa.y) + (fb.x + fb.y));
        gs[c][wp] = sigmoidf_(fmaf(mx + av, gw, gb));
    }
    __syncthreads();

    // ---- phase 3: convert->LDS slices, MFMA; two half-passes ----
    const int q4   = l & 7;                       // px quad id
    const int pxb  = 4 * q4;                      // px base within group
    const int wp0  = 16 * (wv & 1) + 2 * q4;      // gate col (even -> float2 ok)
    const int xoff = (wv >> 1) * 64 + 32 * (wv & 1) + pxb;
    const int cgrp = l >> 3;                      // channel pair group 0..7

    #pragma unroll
    for (int half = 0; half < 2; ++half) {
        #pragma unroll
        for (int cc = 0; cc < 2; ++cc) {
            const int kr = 2 * cgrp + cc;         // slice-local k row 0..15
            const int c  = 16 * half + kr;
            const float4 v = *(const float4*)&xs[c][xoff];
            const float2 g = *(const float2*)&gs[c][wp0];
            uint2 hi, lo;
            // xg = x * gate  (quantity 0 -> slices s = half)
            split4(v.x * g.x, v.y * g.x, v.z * g.y, v.w * g.y, hi, lo);
            *(uint2_ma*)&Bb[wv][kr * 36 + pxb]        = hi;
            *(uint2_ma*)&Bb[wv][576 + kr * 36 + pxb]  = lo;
            // xv = x        (quantity 1 -> slices s = 2+half)
            split4(v.x, v.y, v.z, v.w, hi, lo);
            *(uint2_ma*)&Bb[wv][1152 + kr * 36 + pxb] = hi;
            *(uint2_ma*)&Bb[wv][1728 + kr * 36 + pxb] = lo;
        }
        #pragma unroll
        for (int qq = 0; qq < 2; ++qq) {
            const int s  = 2 * qq + half;
            const int fb = qq * 1152 + 288 * j + (l & 31);
            s8v fh, fl;
            #pragma unroll
            for (int q = 0; q < 8; ++q) {
                fh[q] = (short)Bb[wv][fb + 36 * q];
                fl[q] = (short)Bb[wv][fb + 576 + 36 * q];
            }
            acc = __builtin_amdgcn_mfma_f32_32x32x16_bf16(whi[s], fh, acc, 0, 0, 0);
            acc = __builtin_amdgcn_mfma_f32_32x32x16_bf16(whi[s], fl, acc, 0, 0, 0);
            acc = __builtin_amdgcn_mfma_f32_32x32x16_bf16(wlo[s], fh, acc, 0, 0, 0);
        }
    }

    // ---- epilogue: fs stores + channel max/mean ----
    const int gy = h0 + (wv >> 1);
    const int gx = x0 + 32 * (wv & 1) + (l & 31);
    float cmx = -3.4e38f, csm = 0.0f;
    #pragma unroll
    for (int r = 0; r < 16; ++r) {
        const int oc = (r & 3) + 8 * (r >> 2) + 4 * j;
        fs[((size_t)(b * C + oc) * H + gy) * W + gx] = acc[r];
        cmx = fmaxf(cmx, acc[r]);
        csm += acc[r];
    }
    cmx = fmaxf(cmx, __shfl_xor(cmx, 32));
    csm += __shfl_xor(csm, 32);
    if (l < 32) {
        const size_t pp = ((size_t)b * H + gy) * W + gx;
        cm[pp] = cmx;
        ca[pp] = csm * (1.0f / 32.0f);
    }
}

// ---------------------------------------------------------------------------
// Kernel 2 (UNCHANGED from round 1): 7x7 conv (2ch->32ch SAME) via bf16 split
// MFMA, then out = sigmoid(att)*fs, in place.  Grid MUST be (4, 64, 8):
// x0 = bx*128 covers 512 cols only with bx in [0,4).
// ---------------------------------------------------------------------------
__global__ __launch_bounds__(256, 3) void k2_conv7_mfma(
    const float* __restrict__ cm, const float* __restrict__ ca,
    const float* __restrict__ convout_w, const float* __restrict__ convout_b,
    float* __restrict__ io /* fs in, final out, in-place */)
{
    __shared__ unsigned short win[4 * 14 * 144];   // hi{cm,ca}, lo{cm,ca}
    const int t  = threadIdx.x;
    const int x0 = blockIdx.x * 128;
    const int y0 = blockIdx.y * 8;
    const int b  = blockIdx.z;

    #pragma unroll
    for (int k = 0; k < 16; ++k) {
        int n = k * 256 + t;
        if (n < 4032) {
            int j   = (n >= 2016) ? 1 : 0;
            int rem = n - j * 2016;
            int row = rem / 144;
            int col = rem - row * 144;
            int gy = y0 - 3 + row;
            int gx = x0 - 3 + col;
            float v = 0.0f;
            if ((unsigned)gy < (unsigned)H && (unsigned)gx < (unsigned)W)
                v = (j ? ca : cm)[(size_t)b * HW + (size_t)gy * W + gx];
            unsigned hb = bf16rne(v);
            unsigned lb = bf16rne(v - bf16tof(hb));
            win[n]        = (unsigned short)hb;
            win[n + 4032] = (unsigned short)lb;
        }
    }

    const int l  = t & 63;
    const int wv = t >> 6;          // wave id = strip id
    const int o  = l & 31;          // A row (oc) / B col (px)
    const int j  = l >> 5;          // k-half: input plane select
    s8v whi[7], wlo[7];
    #pragma unroll
    for (int dy = 0; dy < 7; ++dy) {
        #pragma unroll
        for (int q = 0; q < 8; ++q) {
            float wf = (q < 7) ? convout_w[(o * 2 + j) * 49 + dy * 7 + q] : 0.0f;
            unsigned hb = bf16rne(wf);
            unsigned lb = bf16rne(wf - bf16tof(hb));
            whi[dy][q] = (short)hb;
            wlo[dy][q] = (short)lb;
        }
    }
    float bias[16];
    #pragma unroll
    for (int r = 0; r < 16; ++r)
        bias[r] = convout_b[(r & 3) + 8 * (r >> 2) + 4 * j];
    __syncthreads();

    const int xl  = wv * 32 + o;    // local pixel col 0..127
    const int q0  = xl >> 1;        // dword index within row
    const bool odd = (xl & 1) != 0;

    #pragma unroll 1
    for (int y = 0; y < 8; ++y) {
        f16v acc;
        #pragma unroll
        for (int r = 0; r < 16; ++r) acc[r] = bias[r];

        #pragma unroll
        for (int dy = 0; dy < 7; ++dy) {
            const unsigned int* rp =
                (const unsigned int*)win + (size_t)(y + dy) * 72 + j * 1008 + q0;
            unsigned int d0 = rp[0], d1 = rp[1], d2 = rp[2], d3 = rp[3], d4 = rp[4];
            const unsigned int* rp2 = rp + 2016;   // lo planes (+4032 elems)
            unsigned int e0 = rp2[0], e1 = rp2[1], e2 = rp2[2], e3 = rp2[3], e4 = rp2[4];

            union { unsigned int u[4]; s8v s; } Bh, Bl;
            if (odd) {
                Bh.u[0] = (d0 >> 16) | (d1 << 16);
                Bh.u[1] = (d1 >> 16) | (d2 << 16);
                Bh.u[2] = (d2 >> 16) | (d3 << 16);
                Bh.u[3] = (d3 >> 16) | (d4 << 16);
                Bl.u[0] = (e0 >> 16) | (e1 << 16);
                Bl.u[1] = (e1 >> 16) | (e2 << 16);
                Bl.u[2] = (e2 >> 16) | (e3 << 16);
                Bl.u[3] = (e3 >> 16) | (e4 << 16);
            } else {
                Bh.u[0] = d0; Bh.u[1] = d1; Bh.u[2] = d2; Bh.u[3] = d3;
                Bl.u[0] = e0; Bl.u[1] = e1; Bl.u[2] = e2; Bl.u[3] = e3;
            }
            acc = __builtin_amdgcn_mfma_f32_32x32x16_bf16(whi[dy], Bh.s, acc, 0, 0, 0);
            acc = __builtin_amdgcn_mfma_f32_32x32x16_bf16(whi[dy], Bl.s, acc, 0, 0, 0);
            acc = __builtin_amdgcn_mfma_f32_32x32x16_bf16(wlo[dy], Bh.s, acc, 0, 0, 0);
        }

        const int Y = y0 + y;
        const int X = x0 + xl;
        #pragma unroll
        for (int r = 0; r < 16; ++r) {
            int oc = (r & 3) + 8 * (r >> 2) + 4 * j;
            size_t a = ((size_t)(b * C + oc) * H + Y) * W + X;
            float f = io[a];
            io[a] = f * sigmoidf_(acc[r]);
        }
    }
}

extern "C" void kernel_launch(void* const* d_in, const int* in_sizes, int n_in,
                              void* d_out, int out_size, void* d_ws, size_t ws_size,
                              hipStream_t stream)
{
    const float* x         = (const float*)d_in[0];
    const float* mlp_w     = (const float*)d_in[1];
    const float* mlp_b     = (const float*)d_in[2];
    const float* conv_w    = (const float*)d_in[3];
    const float* conv_b    = (const float*)d_in[4];
    const float* convout_w = (const float*)d_in[5];
    const float* convout_b = (const float*)d_in[6];

    float* out = (float*)d_out;             // fs lives here between kernels
    float* cm  = (float*)d_ws;              // 8 MiB
    float* ca  = cm + (size_t)B * HW;       // 8 MiB (ws needs 16 MiB)

    k1_gate_conv_mfma<<<dim3(8, 256, 8), 256, 0, stream>>>(
        x, mlp_w, mlp_b, conv_w, conv_b, out, cm, ca);
    k2_conv7_mfma<<<dim3(4, 64, 8), 256, 0, stream>>>(
        cm, ca, convout_w, convout_b, out);
}